// Round 1
// baseline (259.484 us; speedup 1.0000x reference)
//
#include <hip/hip_runtime.h>
#include <math.h>

// ---------------- constants ----------------
#define WS 11
#define PAD 10          // WS-1
#define TW 32           // output tile width
#define TH 32           // output tile height
#define IW (TW + PAD)   // 42
#define IH (TH + PAD)   // 42
#define NC 48           // 16 batch * 3 channels
#define C1V 1.0e-4f
#define C2V 9.0e-4f

struct GaussW { float g[WS]; };

// ---------------- fused per-level SSIM kernel ----------------
// grid: (tiles*tiles, NC); block: 256
__global__ __launch_bounds__(256) void ssim_level_kernel(
    const float* __restrict__ img1, const float* __restrict__ img2,
    int H, int W, int OH, int OW, int tilesX,
    GaussW gw, float2* __restrict__ partial)
{
    __shared__ float s1[IH][IW];
    __shared__ float s2[IH][IW];
    __shared__ float r0[IH][TW];   // row-conv mu1
    __shared__ float r1[IH][TW];   // row-conv mu2
    __shared__ float r2[IH][TW];   // row-conv E[x^2]
    __shared__ float r3[IH][TW];   // row-conv E[y^2]
    __shared__ float r4[IH][TW];   // row-conv E[xy]
    __shared__ float reds[4], redc[4];

    const int tid  = threadIdx.x;
    const int tileX = blockIdx.x % tilesX;
    const int tileY = blockIdx.x / tilesX;
    const int img   = blockIdx.y;

    const float* __restrict__ p1 = img1 + (size_t)img * H * W;
    const float* __restrict__ p2 = img2 + (size_t)img * H * W;

    const int ox0 = tileX * TW;
    const int oy0 = tileY * TH;

    // ---- load input tile (with zero fill at borders) ----
    for (int idx = tid; idx < IH * IW; idx += 256) {
        int r = idx / IW, c = idx - r * IW;
        int y = oy0 + r, x = ox0 + c;
        float a = 0.f, b = 0.f;
        if (y < H && x < W) {
            a = p1[(size_t)y * W + x];
            b = p2[(size_t)y * W + x];
        }
        s1[r][c] = a; s2[r][c] = b;
    }
    __syncthreads();

    // ---- horizontal (row) convolution of the 5 channels ----
    for (int idx = tid; idx < IH * TW; idx += 256) {
        int r = idx >> 5, c = idx & 31;
        float m1 = 0.f, m2 = 0.f, e11 = 0.f, e22 = 0.f, e12 = 0.f;
#pragma unroll
        for (int k = 0; k < WS; ++k) {
            float g = gw.g[k];
            float a = s1[r][c + k];
            float b = s2[r][c + k];
            m1  += g * a;
            m2  += g * b;
            e11 += g * a * a;
            e22 += g * b * b;
            e12 += g * a * b;
        }
        r0[r][c] = m1; r1[r][c] = m2; r2[r][c] = e11; r3[r][c] = e22; r4[r][c] = e12;
    }
    __syncthreads();

    // ---- vertical (col) convolution + SSIM map + local accumulation ----
    float ssim_acc = 0.f, cs_acc = 0.f;
    for (int idx = tid; idx < TH * TW; idx += 256) {
        int r = idx >> 5, c = idx & 31;
        int oy = oy0 + r, ox = ox0 + c;
        if (oy < OH && ox < OW) {
            float mu1 = 0.f, mu2 = 0.f, e11 = 0.f, e22 = 0.f, e12 = 0.f;
#pragma unroll
            for (int k = 0; k < WS; ++k) {
                float g = gw.g[k];
                mu1 += g * r0[r + k][c];
                mu2 += g * r1[r + k][c];
                e11 += g * r2[r + k][c];
                e22 += g * r3[r + k][c];
                e12 += g * r4[r + k][c];
            }
            float mu1sq = mu1 * mu1;
            float mu2sq = mu2 * mu2;
            float mu12  = mu1 * mu2;
            float sig1  = e11 - mu1sq;
            float sig2  = e22 - mu2sq;
            float sig12 = e12 - mu12;
            float v1 = 2.f * sig12 + C2V;
            float v2 = sig1 + sig2 + C2V;
            float cs   = v1 / v2;
            float ssim = (2.f * mu12 + C1V) * v1 / ((mu1sq + mu2sq + C1V) * v2);
            ssim_acc += ssim;
            cs_acc   += cs;
        }
    }

    // ---- deterministic block reduction ----
#pragma unroll
    for (int off = 32; off > 0; off >>= 1) {
        ssim_acc += __shfl_down(ssim_acc, off);
        cs_acc   += __shfl_down(cs_acc, off);
    }
    int wave = tid >> 6, lane = tid & 63;
    if (lane == 0) { reds[wave] = ssim_acc; redc[wave] = cs_acc; }
    __syncthreads();
    if (tid == 0) {
        float s = reds[0] + reds[1] + reds[2] + reds[3];
        float c = redc[0] + redc[1] + redc[2] + redc[3];
        partial[(size_t)blockIdx.y * gridDim.x + blockIdx.x] = make_float2(s, c);
    }
}

// ---------------- deterministic partial reduction ----------------
__global__ __launch_bounds__(256) void reduce_kernel(
    const float2* __restrict__ partial, int n, float inv_count,
    float2* __restrict__ result)
{
    __shared__ float reds[4], redc[4];
    int tid = threadIdx.x;
    float s = 0.f, c = 0.f;
    for (int i = tid; i < n; i += 256) {
        float2 v = partial[i];
        s += v.x; c += v.y;
    }
#pragma unroll
    for (int off = 32; off > 0; off >>= 1) {
        s += __shfl_down(s, off);
        c += __shfl_down(c, off);
    }
    int wave = tid >> 6, lane = tid & 63;
    if (lane == 0) { reds[wave] = s; redc[wave] = c; }
    __syncthreads();
    if (tid == 0) {
        s = reds[0] + reds[1] + reds[2] + reds[3];
        c = redc[0] + redc[1] + redc[2] + redc[3];
        *result = make_float2(s * inv_count, c * inv_count);
    }
}

// ---------------- 2x2 average pool (both images at once) ----------------
__global__ __launch_bounds__(256) void pool_kernel(
    const float* __restrict__ in1, const float* __restrict__ in2,
    float* __restrict__ out1, float* __restrict__ out2,
    int h, int w, int total)
{
    int idx = blockIdx.x * 256 + threadIdx.x;
    if (idx >= total) return;
    int x = idx % w;
    int t = idx / w;
    int y = t % h;
    int img = t / h;
    int W = w * 2, H = h * 2;
    size_t base = (size_t)img * H * W + (size_t)(2 * y) * W + 2 * x;
    const float2* a0 = (const float2*)(in1 + base);
    const float2* a1 = (const float2*)(in1 + base + W);
    const float2* b0 = (const float2*)(in2 + base);
    const float2* b1 = (const float2*)(in2 + base + W);
    float2 va0 = *a0, va1 = *a1, vb0 = *b0, vb1 = *b1;
    size_t obase = (size_t)img * h * w + (size_t)y * w + x;
    out1[obase] = 0.25f * (va0.x + va0.y + va1.x + va1.y);
    out2[obase] = 0.25f * (vb0.x + vb0.y + vb1.x + vb1.y);
}

// ---------------- final weighted product ----------------
__global__ void final_kernel(const float2* __restrict__ results, float* __restrict__ out)
{
    if (threadIdx.x == 0 && blockIdx.x == 0) {
        const float w[5] = {0.0448f, 0.2856f, 0.3001f, 0.2363f, 0.1333f};
        float prod = 1.f;
#pragma unroll
        for (int i = 0; i < 4; ++i) {
            float mcs = (results[i].y + 1.f) * 0.5f;
            prod *= powf(mcs, w[i]);
        }
        float mssim = (results[4].x + 1.f) * 0.5f;
        prod *= powf(mssim, w[4]);
        out[0] = prod;
    }
}

// ---------------- host launch ----------------
extern "C" void kernel_launch(void* const* d_in, const int* in_sizes, int n_in,
                              void* d_out, int out_size, void* d_ws, size_t ws_size,
                              hipStream_t stream)
{
    const float* img1 = (const float*)d_in[0];
    const float* img2 = (const float*)d_in[1];
    float* out = (float*)d_out;
    float* ws  = (float*)d_ws;

    // Gaussian window (sigma = 1.5), normalized
    GaussW gw;
    {
        double g[WS], sum = 0.0;
        for (int i = 0; i < WS; ++i) {
            double x = (double)i - (WS / 2);
            g[i] = exp(-x * x / (2.0 * 1.5 * 1.5));
            sum += g[i];
        }
        for (int i = 0; i < WS; ++i) gw.g[i] = (float)(g[i] / sum);
    }

    // workspace layout
    float* p1[5]; float* p2[5];
    p1[0] = nullptr; p2[0] = nullptr;
    size_t o = 0;
    for (int l = 1; l < 5; ++l) {
        int H = 512 >> l;
        p1[l] = ws + o; o += (size_t)NC * H * H;
        p2[l] = ws + o; o += (size_t)NC * H * H;
    }
    float2* partial = (float2*)(ws + o); o += 2 * 12288;
    float2* results = (float2*)(ws + o); o += 2 * 5;
    (void)ws_size;

    for (int l = 0; l < 5; ++l) {
        int H = 512 >> l;
        int OH = H - PAD;
        int tiles = (OH + TW - 1) / TW;
        const float* a = l ? p1[l] : img1;
        const float* b = l ? p2[l] : img2;

        dim3 grid(tiles * tiles, NC);
        ssim_level_kernel<<<grid, 256, 0, stream>>>(a, b, H, H, OH, OH, tiles, gw, partial);

        int nPart = tiles * tiles * NC;
        float inv = 1.f / ((float)NC * OH * OH);
        reduce_kernel<<<1, 256, 0, stream>>>(partial, nPart, inv, results + l);

        if (l < 4) {
            int h = H >> 1;
            int total = NC * h * h;
            pool_kernel<<<(total + 255) / 256, 256, 0, stream>>>(a, b, p1[l + 1], p2[l + 1], h, h, total);
        }
    }

    final_kernel<<<1, 64, 0, stream>>>(results, out);
}

// Round 2
// 131.973 us; speedup vs baseline: 1.9662x; 1.9662x over previous
//
#include <hip/hip_runtime.h>
#include <math.h>

// ---------------- constants ----------------
#define WS 11
#define PAD 10
#define TW 32
#define TH 32
#define IH 42          // TH + PAD input rows per tile
#define RST 33         // row-plane stride (33 -> conflict-free for both phases)
#define NC 48          // 16 batch * 3 channels
#define C1V 1.0e-4f
#define C2V 9.0e-4f

struct Params { float g[WS]; };
struct ROff { int off[5]; int cnt[5]; float inv[5]; };

// ---------------- fused per-level SSIM (+pool) kernel ----------------
// grid: (tiles*tiles, NC); block: 256
template<int POOL>
__global__ __launch_bounds__(256, 4) void ssim_level_kernel(
    const float* __restrict__ img1, const float* __restrict__ img2,
    float* __restrict__ pool1, float* __restrict__ pool2,
    int H, int OH, int tilesX, Params P,
    float2* __restrict__ partial, int partial_off)
{
    __shared__ float rp[5][IH][RST];   // row-conv planes: mu1, mu2, Exx, Eyy, Exy
    __shared__ float reds[4], redc[4];

    const int tid   = threadIdx.x;
    const int tileX = blockIdx.x % tilesX;
    const int tileY = blockIdx.x / tilesX;
    const int img   = blockIdx.y;
    const size_t ib = (size_t)img * H * H;
    const float* __restrict__ p1 = img1 + ib;
    const float* __restrict__ p2 = img2 + ib;
    const int ox0 = tileX * TW;
    const int oy0 = tileY * TH;

    // ---- row (horizontal) convolution: 42 rows x 8 groups of 4 output cols ----
    // Each unit loads a 16-float window per image (4x float4, clamped: wrong-position
    // data only ever feeds outputs that are excluded by the OH/OW guards below).
    for (int u = tid; u < IH * 8; u += 256) {
        const int r  = u >> 3, cg = u & 7;
        const int y  = min(oy0 + r, H - 1);
        const float* __restrict__ rowa = p1 + (size_t)y * H;
        const float* __restrict__ rowb = p2 + (size_t)y * H;
        float a[16], b[16];
#pragma unroll
        for (int q = 0; q < 4; ++q) {
            int x = min(ox0 + cg * 4 + q * 4, H - 4);   // H%4==0 -> stays 16B aligned
            const float4 va = *(const float4*)(rowa + x);
            const float4 vb = *(const float4*)(rowb + x);
            a[q*4+0]=va.x; a[q*4+1]=va.y; a[q*4+2]=va.z; a[q*4+3]=va.w;
            b[q*4+0]=vb.x; b[q*4+1]=vb.y; b[q*4+2]=vb.z; b[q*4+3]=vb.w;
        }
        float m1[4]  = {0,0,0,0}, m2[4]  = {0,0,0,0};
        float e11[4] = {0,0,0,0}, e22[4] = {0,0,0,0}, e12[4] = {0,0,0,0};
#pragma unroll
        for (int i = 0; i < 14; ++i) {
            const float av = a[i], bv = b[i];
            const float aa = av*av, bb = bv*bv, ab = av*bv;  // products once per input
#pragma unroll
            for (int j = 0; j < 4; ++j) {
                const int k = i - j;
                if (k >= 0 && k < WS) {
                    const float g = P.g[k];
                    m1[j]  += g * av; m2[j]  += g * bv;
                    e11[j] += g * aa; e22[j] += g * bb; e12[j] += g * ab;
                }
            }
        }
        const int c0 = cg * 4;
#pragma unroll
        for (int j = 0; j < 4; ++j) {
            rp[0][r][c0+j] = m1[j];
            rp[1][r][c0+j] = m2[j];
            rp[2][r][c0+j] = e11[j];
            rp[3][r][c0+j] = e22[j];
            rp[4][r][c0+j] = e12[j];
        }
    }
    __syncthreads();

    // ---- column convolution + SSIM map, 4 consecutive output rows per thread ----
    const int c  = tid & 31;
    const int r0 = (tid >> 5) * 4;     // 0,4,...,28
    float A0[4]={0,0,0,0}, A1[4]={0,0,0,0}, A2[4]={0,0,0,0};
    float A3[4]={0,0,0,0}, A4[4]={0,0,0,0};
#pragma unroll
    for (int k = 0; k < 14; ++k) {
        const float v0 = rp[0][r0+k][c];
        const float v1 = rp[1][r0+k][c];
        const float v2 = rp[2][r0+k][c];
        const float v3 = rp[3][r0+k][c];
        const float v4 = rp[4][r0+k][c];
#pragma unroll
        for (int j = 0; j < 4; ++j) {
            const int t = k - j;
            if (t >= 0 && t < WS) {
                const float g = P.g[t];
                A0[j]+=g*v0; A1[j]+=g*v1; A2[j]+=g*v2; A3[j]+=g*v3; A4[j]+=g*v4;
            }
        }
    }
    float ssim_acc = 0.f, cs_acc = 0.f;
    const int ox = ox0 + c;
#pragma unroll
    for (int j = 0; j < 4; ++j) {
        const int oy = oy0 + r0 + j;
        if (oy < OH && ox < OH) {      // OW == OH (square)
            const float mu1 = A0[j], mu2 = A1[j];
            const float mu1sq = mu1*mu1, mu2sq = mu2*mu2, mu12 = mu1*mu2;
            const float v1 = 2.f*(A4[j] - mu12) + C2V;
            const float v2 = (A2[j] - mu1sq) + (A3[j] - mu2sq) + C2V;
            const float rv2 = __builtin_amdgcn_rcpf(v2);
            const float cs  = v1 * rv2;
            const float den = mu1sq + mu2sq + C1V;
            const float ssim = (2.f*mu12 + C1V) * v1 * __builtin_amdgcn_rcpf(den) * rv2;
            ssim_acc += ssim;
            cs_acc   += cs;
        }
    }

    // ---- fused 2x2 avg pool of the tile's 32x32 core (covers grid exactly once) ----
    if (POOL) {
        const int px = tid & 15, py = tid >> 4;
        const int yy = oy0 + 2 * py;
        const int xx = ox0 + 2 * px;
        const float2 a0 = *(const float2*)(p1 + (size_t)yy * H + xx);
        const float2 a1 = *(const float2*)(p1 + (size_t)(yy+1) * H + xx);
        const float2 b0 = *(const float2*)(p2 + (size_t)yy * H + xx);
        const float2 b1 = *(const float2*)(p2 + (size_t)(yy+1) * H + xx);
        const int h = H >> 1;
        const size_t ob = (size_t)img * h * h + (size_t)((oy0 >> 1) + py) * h + (ox0 >> 1) + px;
        pool1[ob] = 0.25f * (a0.x + a0.y + a1.x + a1.y);
        pool2[ob] = 0.25f * (b0.x + b0.y + b1.x + b1.y);
    }

    // ---- deterministic block reduction -> one partial per block ----
#pragma unroll
    for (int off = 32; off > 0; off >>= 1) {
        ssim_acc += __shfl_down(ssim_acc, off);
        cs_acc   += __shfl_down(cs_acc, off);
    }
    const int wave = tid >> 6, lane = tid & 63;
    if (lane == 0) { reds[wave] = ssim_acc; redc[wave] = cs_acc; }
    __syncthreads();
    if (tid == 0) {
        const float s = reds[0] + reds[1] + reds[2] + reds[3];
        const float cc = redc[0] + redc[1] + redc[2] + redc[3];
        partial[(size_t)partial_off + (size_t)blockIdx.y * gridDim.x + blockIdx.x] =
            make_float2(s, cc);
    }
}

// ---------------- single fused reduce over all levels + final product ----------------
__global__ __launch_bounds__(256) void reduce_final_kernel(
    const float2* __restrict__ partial, ROff ro, float* __restrict__ out)
{
    __shared__ float sS[5], sC[5];
    __shared__ float reds[4], redc[4];
    const int tid = threadIdx.x;
    for (int l = 0; l < 5; ++l) {
        float s = 0.f, c = 0.f;
        for (int i = tid; i < ro.cnt[l]; i += 256) {
            const float2 v = partial[ro.off[l] + i];
            s += v.x; c += v.y;
        }
#pragma unroll
        for (int off = 32; off > 0; off >>= 1) {
            s += __shfl_down(s, off);
            c += __shfl_down(c, off);
        }
        const int wave = tid >> 6, lane = tid & 63;
        if (lane == 0) { reds[wave] = s; redc[wave] = c; }
        __syncthreads();
        if (tid == 0) {
            sS[l] = (reds[0]+reds[1]+reds[2]+reds[3]) * ro.inv[l];
            sC[l] = (redc[0]+redc[1]+redc[2]+redc[3]) * ro.inv[l];
        }
        __syncthreads();
    }
    if (tid == 0) {
        const float w[5] = {0.0448f, 0.2856f, 0.3001f, 0.2363f, 0.1333f};
        float prod = 1.f;
#pragma unroll
        for (int i = 0; i < 4; ++i)
            prod *= powf((sC[i] + 1.f) * 0.5f, w[i]);
        prod *= powf((sS[4] + 1.f) * 0.5f, w[4]);
        out[0] = prod;
    }
}

// ---------------- host launch ----------------
extern "C" void kernel_launch(void* const* d_in, const int* in_sizes, int n_in,
                              void* d_out, int out_size, void* d_ws, size_t ws_size,
                              hipStream_t stream)
{
    const float* img1 = (const float*)d_in[0];
    const float* img2 = (const float*)d_in[1];
    float* out = (float*)d_out;
    float* ws  = (float*)d_ws;

    // Gaussian window (sigma = 1.5), normalized
    Params P;
    {
        double g[WS], sum = 0.0;
        for (int i = 0; i < WS; ++i) {
            double x = (double)i - (WS / 2);
            g[i] = exp(-x * x / (2.0 * 1.5 * 1.5));
            sum += g[i];
        }
        for (int i = 0; i < WS; ++i) P.g[i] = (float)(g[i] / sum);
    }

    // workspace layout: pyramid levels 1..4 (both images), then partials
    float* p1[5]; float* p2[5];
    p1[0] = (float*)img1; p2[0] = (float*)img2;
    size_t o = 0;
    for (int l = 1; l < 5; ++l) {
        const int H = 512 >> l;
        p1[l] = ws + o; o += (size_t)NC * H * H;
        p2[l] = ws + o; o += (size_t)NC * H * H;
    }
    float2* partial = (float2*)(ws + o);
    (void)ws_size; (void)in_sizes; (void)n_in; (void)out_size;

    ROff ro;
    {
        int off = 0;
        for (int l = 0; l < 5; ++l) {
            const int H = 512 >> l, OH = H - PAD;
            const int tiles = (OH + TW - 1) / TW;
            ro.off[l] = off;
            ro.cnt[l] = tiles * tiles * NC;
            ro.inv[l] = 1.f / ((float)NC * OH * OH);
            off += ro.cnt[l];
        }
    }

    for (int l = 0; l < 5; ++l) {
        const int H = 512 >> l, OH = H - PAD;
        const int tiles = (OH + TW - 1) / TW;
        const dim3 grid(tiles * tiles, NC);
        if (l < 4)
            ssim_level_kernel<1><<<grid, 256, 0, stream>>>(
                p1[l], p2[l], p1[l+1], p2[l+1], H, OH, tiles, P, partial, ro.off[l]);
        else
            ssim_level_kernel<0><<<grid, 256, 0, stream>>>(
                p1[l], p2[l], nullptr, nullptr, H, OH, tiles, P, partial, ro.off[l]);
    }

    reduce_final_kernel<<<1, 256, 0, stream>>>(partial, ro, out);
}

// Round 3
// 119.741 us; speedup vs baseline: 2.1671x; 1.1022x over previous
//
#include <hip/hip_runtime.h>
#include <math.h>

// ---------------- constants ----------------
#define WS 11
#define PAD 10
#define TW 32
#define TH 32
#define IH 42          // TH + PAD input rows per tile
#define NC 48          // 16 batch * 3 channels
#define C1V 1.0e-4f
#define C2V 9.0e-4f

struct Params { float g[WS]; };
struct ROff { int off[5]; int cnt[5]; float inv[5]; };

// ---------------- fused per-level SSIM (+pool) kernel ----------------
// grid: (tiles*tiles, NC); block: 256
// Channels via sum/difference transform: s=a+b, d=a-b; convolve (s, d, s^2, d^2)
// -> one float4 LDS plane instead of five scalar planes.
template<int POOL>
__global__ __launch_bounds__(256, 6) void ssim_level_kernel(
    const float* __restrict__ img1, const float* __restrict__ img2,
    float* __restrict__ pool1, float* __restrict__ pool2,
    int H, int OH, int tilesX, Params P,
    float2* __restrict__ partial, int partial_off)
{
    __shared__ float4 rp[IH][TW];   // (ms, md, Es2, Ed2); col index XOR-swizzled by row&7
    __shared__ float reds[4], redc[4];

    const int tid   = threadIdx.x;
    const int tileX = blockIdx.x % tilesX;
    const int tileY = blockIdx.x / tilesX;
    const int img   = blockIdx.y;
    const size_t ib = (size_t)img * H * H;
    const float* __restrict__ p1 = img1 + ib;
    const float* __restrict__ p2 = img2 + ib;
    const int ox0 = tileX * TW;
    const int oy0 = tileY * TH;

    // ---- row (horizontal) convolution: 42 rows x 8 groups of 4 output cols ----
    // Clamped loads only ever feed outputs excluded by the OH guards below.
    for (int u = tid; u < IH * 8; u += 256) {
        const int r = u >> 3, cg = u & 7;
        const int y = min(oy0 + r, H - 1);
        const float* __restrict__ rowa = p1 + (size_t)y * H;
        const float* __restrict__ rowb = p2 + (size_t)y * H;
        float sv[16], dv[16];
#pragma unroll
        for (int q = 0; q < 4; ++q) {
            const int x = min(ox0 + cg * 4 + q * 4, H - 4);   // H%4==0 -> 16B aligned
            const float4 va = *(const float4*)(rowa + x);
            const float4 vb = *(const float4*)(rowb + x);
            sv[q*4+0] = va.x + vb.x;  dv[q*4+0] = va.x - vb.x;
            sv[q*4+1] = va.y + vb.y;  dv[q*4+1] = va.y - vb.y;
            sv[q*4+2] = va.z + vb.z;  dv[q*4+2] = va.z - vb.z;
            sv[q*4+3] = va.w + vb.w;  dv[q*4+3] = va.w - vb.w;
        }
        float m0[4] = {0,0,0,0}, m1[4] = {0,0,0,0};
        float m2[4] = {0,0,0,0}, m3[4] = {0,0,0,0};
#pragma unroll
        for (int i = 0; i < 14; ++i) {
            const float s = sv[i], d = dv[i];
            const float ss = s * s, dd = d * d;
#pragma unroll
            for (int j = 0; j < 4; ++j) {
                const int k = i - j;
                if (k >= 0 && k < WS) {
                    const float g = P.g[k];
                    m0[j] += g * s;  m1[j] += g * d;
                    m2[j] += g * ss; m3[j] += g * dd;
                }
            }
        }
        const int c0 = cg * 4, sw = r & 7;
#pragma unroll
        for (int j = 0; j < 4; ++j)
            rp[r][(c0 + j) ^ sw] = make_float4(m0[j], m1[j], m2[j], m3[j]);
    }
    __syncthreads();

    // ---- column convolution + SSIM map, 4 consecutive output rows per thread ----
    const int c  = tid & 31;
    const int r0 = (tid >> 5) * 4;     // 0,4,...,28
    float A0[4]={0,0,0,0}, A1[4]={0,0,0,0}, A2[4]={0,0,0,0}, A3[4]={0,0,0,0};
#pragma unroll
    for (int k = 0; k < 14; ++k) {
        const int R = r0 + k;
        const float4 v = rp[R][c ^ (R & 7)];
#pragma unroll
        for (int j = 0; j < 4; ++j) {
            const int t = k - j;
            if (t >= 0 && t < WS) {
                const float g = P.g[t];
                A0[j] += g * v.x; A1[j] += g * v.y;
                A2[j] += g * v.z; A3[j] += g * v.w;
            }
        }
    }
    float ssim_acc = 0.f, cs_acc = 0.f;
    const int ox = ox0 + c;
#pragma unroll
    for (int j = 0; j < 4; ++j) {
        const int oy = oy0 + r0 + j;
        if (oy < OH && ox < OH) {      // OW == OH (square)
            const float ms = A0[j], md = A1[j], Es = A2[j], Ed = A3[j];
            const float ms2 = ms * ms, md2 = md * md;
            const float mu12 = 0.25f * (ms2 - md2);
            const float musq = 0.5f  * (ms2 + md2);          // mu1^2 + mu2^2
            const float v1 = 0.5f * (Es - Ed) - 2.f * mu12 + C2V;  // 2*sig12 + C2
            const float v2 = 0.5f * (Es + Ed) - musq + C2V;        // sig1+sig2 + C2
            const float rv2 = __builtin_amdgcn_rcpf(v2);
            const float cs  = v1 * rv2;
            const float ssim = (2.f * mu12 + C1V) *
                               __builtin_amdgcn_rcpf(musq + C1V) * cs;
            ssim_acc += ssim;
            cs_acc   += cs;
        }
    }

    // ---- fused 2x2 avg pool of the tile's 32x32 core (covers grid exactly once) ----
    if (POOL) {
        const int px = tid & 15, py = tid >> 4;
        const int yy = oy0 + 2 * py;
        const int xx = ox0 + 2 * px;
        const float2 a0 = *(const float2*)(p1 + (size_t)yy * H + xx);
        const float2 a1 = *(const float2*)(p1 + (size_t)(yy + 1) * H + xx);
        const float2 b0 = *(const float2*)(p2 + (size_t)yy * H + xx);
        const float2 b1 = *(const float2*)(p2 + (size_t)(yy + 1) * H + xx);
        const int h = H >> 1;
        const size_t ob = (size_t)img * h * h + (size_t)((oy0 >> 1) + py) * h + (ox0 >> 1) + px;
        pool1[ob] = 0.25f * (a0.x + a0.y + a1.x + a1.y);
        pool2[ob] = 0.25f * (b0.x + b0.y + b1.x + b1.y);
    }

    // ---- deterministic block reduction -> one partial per block ----
#pragma unroll
    for (int off = 32; off > 0; off >>= 1) {
        ssim_acc += __shfl_down(ssim_acc, off);
        cs_acc   += __shfl_down(cs_acc, off);
    }
    const int wave = tid >> 6, lane = tid & 63;
    if (lane == 0) { reds[wave] = ssim_acc; redc[wave] = cs_acc; }
    __syncthreads();
    if (tid == 0) {
        const float s  = reds[0] + reds[1] + reds[2] + reds[3];
        const float cc = redc[0] + redc[1] + redc[2] + redc[3];
        partial[(size_t)partial_off + (size_t)blockIdx.y * gridDim.x + blockIdx.x] =
            make_float2(s, cc);
    }
}

// ---------------- single fused reduce over all levels + final product ----------------
__global__ __launch_bounds__(256) void reduce_final_kernel(
    const float2* __restrict__ partial, ROff ro, float* __restrict__ out)
{
    __shared__ float sS[5], sC[5];
    __shared__ float reds[4], redc[4];
    const int tid = threadIdx.x;
    for (int l = 0; l < 5; ++l) {
        float s = 0.f, c = 0.f;
        for (int i = tid; i < ro.cnt[l]; i += 256) {
            const float2 v = partial[ro.off[l] + i];
            s += v.x; c += v.y;
        }
#pragma unroll
        for (int off = 32; off > 0; off >>= 1) {
            s += __shfl_down(s, off);
            c += __shfl_down(c, off);
        }
        const int wave = tid >> 6, lane = tid & 63;
        if (lane == 0) { reds[wave] = s; redc[wave] = c; }
        __syncthreads();
        if (tid == 0) {
            sS[l] = (reds[0] + reds[1] + reds[2] + reds[3]) * ro.inv[l];
            sC[l] = (redc[0] + redc[1] + redc[2] + redc[3]) * ro.inv[l];
        }
        __syncthreads();
    }
    if (tid == 0) {
        const float w[5] = {0.0448f, 0.2856f, 0.3001f, 0.2363f, 0.1333f};
        float prod = 1.f;
#pragma unroll
        for (int i = 0; i < 4; ++i)
            prod *= powf((sC[i] + 1.f) * 0.5f, w[i]);
        prod *= powf((sS[4] + 1.f) * 0.5f, w[4]);
        out[0] = prod;
    }
}

// ---------------- host launch ----------------
extern "C" void kernel_launch(void* const* d_in, const int* in_sizes, int n_in,
                              void* d_out, int out_size, void* d_ws, size_t ws_size,
                              hipStream_t stream)
{
    const float* img1 = (const float*)d_in[0];
    const float* img2 = (const float*)d_in[1];
    float* out = (float*)d_out;
    float* ws  = (float*)d_ws;

    // Gaussian window (sigma = 1.5), normalized
    Params P;
    {
        double g[WS], sum = 0.0;
        for (int i = 0; i < WS; ++i) {
            double x = (double)i - (WS / 2);
            g[i] = exp(-x * x / (2.0 * 1.5 * 1.5));
            sum += g[i];
        }
        for (int i = 0; i < WS; ++i) P.g[i] = (float)(g[i] / sum);
    }

    // workspace layout: pyramid levels 1..4 (both images), then partials
    float* p1[5]; float* p2[5];
    p1[0] = (float*)img1; p2[0] = (float*)img2;
    size_t o = 0;
    for (int l = 1; l < 5; ++l) {
        const int H = 512 >> l;
        p1[l] = ws + o; o += (size_t)NC * H * H;
        p2[l] = ws + o; o += (size_t)NC * H * H;
    }
    float2* partial = (float2*)(ws + o);
    (void)ws_size; (void)in_sizes; (void)n_in; (void)out_size;

    ROff ro;
    {
        int off = 0;
        for (int l = 0; l < 5; ++l) {
            const int H = 512 >> l, OH = H - PAD;
            const int tiles = (OH + TW - 1) / TW;
            ro.off[l] = off;
            ro.cnt[l] = tiles * tiles * NC;
            ro.inv[l] = 1.f / ((float)NC * OH * OH);
            off += ro.cnt[l];
        }
    }

    for (int l = 0; l < 5; ++l) {
        const int H = 512 >> l, OH = H - PAD;
        const int tiles = (OH + TW - 1) / TW;
        const dim3 grid(tiles * tiles, NC);
        if (l < 4)
            ssim_level_kernel<1><<<grid, 256, 0, stream>>>(
                p1[l], p2[l], p1[l + 1], p2[l + 1], H, OH, tiles, P, partial, ro.off[l]);
        else
            ssim_level_kernel<0><<<grid, 256, 0, stream>>>(
                p1[l], p2[l], nullptr, nullptr, H, OH, tiles, P, partial, ro.off[l]);
    }

    reduce_final_kernel<<<1, 256, 0, stream>>>(partial, ro, out);
}

// Round 4
// 105.126 us; speedup vs baseline: 2.4683x; 1.1390x over previous
//
#include <hip/hip_runtime.h>
#include <math.h>

// ---------------- constants ----------------
#define WS 11
#define PAD 10
#define NC 48            // 16 batch * 3 channels
#define C1V 1.0e-4f
#define C2V 9.0e-4f
#define BROWS 64         // circular LDS row-plane depth (power of 2)
#define RST 33           // float4 row stride (33*16B = 528B; bank shift 4/row)

struct Params { float g[WS]; };
struct ROff { int off[5]; int cnt[5]; float inv[5]; };

// ---- one row-conv unit: 4 output cols, channels (s, d, s^2, d^2) ----
__device__ __forceinline__ void row_conv_unit(
    const float* __restrict__ rowa, const float* __restrict__ rowb,
    const int xq[4], int cg, float4* __restrict__ rprow, const Params& P)
{
    float sv[16], dv[16];
#pragma unroll
    for (int q = 0; q < 4; ++q) {
        const float4 va = *(const float4*)(rowa + xq[q]);
        const float4 vb = *(const float4*)(rowb + xq[q]);
        sv[q*4+0]=va.x+vb.x; dv[q*4+0]=va.x-vb.x;
        sv[q*4+1]=va.y+vb.y; dv[q*4+1]=va.y-vb.y;
        sv[q*4+2]=va.z+vb.z; dv[q*4+2]=va.z-vb.z;
        sv[q*4+3]=va.w+vb.w; dv[q*4+3]=va.w-vb.w;
    }
    float m0[4]={0,0,0,0}, m1[4]={0,0,0,0}, m2[4]={0,0,0,0}, m3[4]={0,0,0,0};
#pragma unroll
    for (int i = 0; i < 14; ++i) {
        const float s = sv[i], d = dv[i];
        const float ss = s*s, dd = d*d;
#pragma unroll
        for (int j = 0; j < 4; ++j) {
            const int k = i - j;
            if (k >= 0 && k < WS) {
                const float g = P.g[k];
                m0[j]+=g*s; m1[j]+=g*d; m2[j]+=g*ss; m3[j]+=g*dd;
            }
        }
    }
#pragma unroll
    for (int j = 0; j < 4; ++j)
        rprow[cg*4 + j] = make_float4(m0[j], m1[j], m2[j], m3[j]);
}

// ---------------- sliding-strip SSIM (+pool) kernel ----------------
// Each block: 32-wide strip, CH chunks of 32 output rows; 64-row circular
// LDS plane of row-conv results. grid: (tilesX*tilesY, NC); block: 256.
template<int CH, int POOL>
__global__ __launch_bounds__(256, 4) void ssim_strip_kernel(
    const float* __restrict__ img1, const float* __restrict__ img2,
    float* __restrict__ pool1, float* __restrict__ pool2,
    int H, int OH, int tilesX, Params P,
    float2* __restrict__ partial, int partial_off)
{
    __shared__ float4 rp[BROWS][RST];
    __shared__ float reds[4], redc[4];
    const int tid   = threadIdx.x;
    const int tileX = blockIdx.x % tilesX;
    const int ty    = blockIdx.x / tilesX;
    const int img   = blockIdx.y;
    const size_t ib = (size_t)img * H * H;
    const float* __restrict__ p1 = img1 + ib;
    const float* __restrict__ p2 = img2 + ib;
    const int ox0 = tileX * 32;
    const int oy0 = ty * (CH * 32);

    // fixed per-thread roles
    const int r_unit = tid >> 3;          // 0..31: row-conv row within chunk
    const int cg     = tid & 7;           // row-conv col group
    int xq[4];                            // clamped, constant across all rows
#pragma unroll
    for (int q = 0; q < 4; ++q) xq[q] = min(ox0 + cg*4 + q*4, H - 4);

    const int cc  = tid & 31;             // col-conv column
    const int r0c = (tid >> 5) * 4;       // col-conv first row in chunk

    // preload strip-relative rows 0..9
    if (tid < 80) {
        const int Y = r_unit;             // 0..9
        const int y = min(oy0 + Y, H - 1);
        row_conv_unit(p1 + (size_t)y*H, p2 + (size_t)y*H, xq, cg,
                      &rp[Y & (BROWS-1)][0], P);
    }

    float ssim_acc = 0.f, cs_acc = 0.f;

    for (int t = 0; t < CH; ++t) {
        // ---- row conv: rows t*32+10 .. t*32+41 (exactly 1 unit/thread) ----
        {
            const int Y = t*32 + 10 + r_unit;
            const int y = min(oy0 + Y, H - 1);
            row_conv_unit(p1 + (size_t)y*H, p2 + (size_t)y*H, xq, cg,
                          &rp[Y & (BROWS-1)][0], P);
        }
        __syncthreads();

        // ---- col conv + SSIM: 4 consecutive rows per thread ----
        float A0[4]={0,0,0,0}, A1[4]={0,0,0,0}, A2[4]={0,0,0,0}, A3[4]={0,0,0,0};
#pragma unroll
        for (int k = 0; k < 14; ++k) {
            const int Y = t*32 + r0c + k;
            const float4 v = rp[Y & (BROWS-1)][cc];
#pragma unroll
            for (int j = 0; j < 4; ++j) {
                const int tt = k - j;
                if (tt >= 0 && tt < WS) {
                    const float g = P.g[tt];
                    A0[j]+=g*v.x; A1[j]+=g*v.y; A2[j]+=g*v.z; A3[j]+=g*v.w;
                }
            }
        }
        const int ox = ox0 + cc;
#pragma unroll
        for (int j = 0; j < 4; ++j) {
            const int oy = oy0 + t*32 + r0c + j;
            if (oy < OH && ox < OH) {     // OW == OH (square)
                const float ms = A0[j], md = A1[j], Es = A2[j], Ed = A3[j];
                const float ms2 = ms*ms, md2 = md*md;
                const float mu12 = 0.25f * (ms2 - md2);
                const float musq = 0.5f  * (ms2 + md2);            // mu1^2+mu2^2
                const float v1 = 0.5f * (Es - Ed) - 2.f*mu12 + C2V; // 2*sig12+C2
                const float v2 = 0.5f * (Es + Ed) - musq + C2V;     // sig1+sig2+C2
                const float rv2 = __builtin_amdgcn_rcpf(v2);
                const float cs  = v1 * rv2;
                const float ssim = (2.f*mu12 + C1V) *
                                   __builtin_amdgcn_rcpf(musq + C1V) * cs;
                ssim_acc += ssim;
                cs_acc   += cs;
            }
        }

        // ---- fused 2x2 avg pool of this chunk's 32x32 core (1 out/thread) ----
        if (POOL) {
            const int px = tid & 15, py = tid >> 4;
            const int yy = oy0 + t*32 + 2*py;
            const int xx = ox0 + 2*px;
            const float2 a0 = *(const float2*)(p1 + (size_t)yy*H + xx);
            const float2 a1 = *(const float2*)(p1 + (size_t)(yy+1)*H + xx);
            const float2 b0 = *(const float2*)(p2 + (size_t)yy*H + xx);
            const float2 b1 = *(const float2*)(p2 + (size_t)(yy+1)*H + xx);
            const int h = H >> 1;
            const size_t ob = (size_t)img*h*h +
                              (size_t)(((oy0 + t*32) >> 1) + py)*h + (ox0 >> 1) + px;
            pool1[ob] = 0.25f * (a0.x + a0.y + a1.x + a1.y);
            pool2[ob] = 0.25f * (b0.x + b0.y + b1.x + b1.y);
        }
        __syncthreads();   // protect read window before next chunk's writes
    }

    // ---- deterministic block reduction -> one partial per block ----
#pragma unroll
    for (int off = 32; off > 0; off >>= 1) {
        ssim_acc += __shfl_down(ssim_acc, off);
        cs_acc   += __shfl_down(cs_acc, off);
    }
    const int wave = tid >> 6, lane = tid & 63;
    if (lane == 0) { reds[wave] = ssim_acc; redc[wave] = cs_acc; }
    __syncthreads();
    if (tid == 0) {
        const float s  = reds[0] + reds[1] + reds[2] + reds[3];
        const float cc2 = redc[0] + redc[1] + redc[2] + redc[3];
        partial[(size_t)partial_off + (size_t)blockIdx.y * gridDim.x + blockIdx.x] =
            make_float2(s, cc2);
    }
}

// ---------------- single fused reduce over all levels + final product ----------------
__global__ __launch_bounds__(256) void reduce_final_kernel(
    const float2* __restrict__ partial, ROff ro, float* __restrict__ out)
{
    __shared__ float sS[5], sC[5];
    __shared__ float reds[4], redc[4];
    const int tid = threadIdx.x;
    for (int l = 0; l < 5; ++l) {
        float s = 0.f, c = 0.f;
        for (int i = tid; i < ro.cnt[l]; i += 256) {
            const float2 v = partial[ro.off[l] + i];
            s += v.x; c += v.y;
        }
#pragma unroll
        for (int off = 32; off > 0; off >>= 1) {
            s += __shfl_down(s, off);
            c += __shfl_down(c, off);
        }
        const int wave = tid >> 6, lane = tid & 63;
        if (lane == 0) { reds[wave] = s; redc[wave] = c; }
        __syncthreads();
        if (tid == 0) {
            sS[l] = (reds[0] + reds[1] + reds[2] + reds[3]) * ro.inv[l];
            sC[l] = (redc[0] + redc[1] + redc[2] + redc[3]) * ro.inv[l];
        }
        __syncthreads();
    }
    if (tid == 0) {
        const float w[5] = {0.0448f, 0.2856f, 0.3001f, 0.2363f, 0.1333f};
        float prod = 1.f;
#pragma unroll
        for (int i = 0; i < 4; ++i)
            prod *= powf((sC[i] + 1.f) * 0.5f, w[i]);
        prod *= powf((sS[4] + 1.f) * 0.5f, w[4]);
        out[0] = prod;
    }
}

// ---------------- host launch ----------------
extern "C" void kernel_launch(void* const* d_in, const int* in_sizes, int n_in,
                              void* d_out, int out_size, void* d_ws, size_t ws_size,
                              hipStream_t stream)
{
    const float* img1 = (const float*)d_in[0];
    const float* img2 = (const float*)d_in[1];
    float* out = (float*)d_out;
    float* ws  = (float*)d_ws;

    // Gaussian window (sigma = 1.5), normalized
    Params P;
    {
        double g[WS], sum = 0.0;
        for (int i = 0; i < WS; ++i) {
            double x = (double)i - (WS / 2);
            g[i] = exp(-x * x / (2.0 * 1.5 * 1.5));
            sum += g[i];
        }
        for (int i = 0; i < WS; ++i) P.g[i] = (float)(g[i] / sum);
    }

    // workspace layout: pyramid levels 1..4 (both images), then partials
    float* p1[5]; float* p2[5];
    p1[0] = (float*)img1; p2[0] = (float*)img2;
    size_t o = 0;
    for (int l = 1; l < 5; ++l) {
        const int H = 512 >> l;
        p1[l] = ws + o; o += (size_t)NC * H * H;
        p2[l] = ws + o; o += (size_t)NC * H * H;
    }
    float2* partial = (float2*)(ws + o);
    (void)ws_size; (void)in_sizes; (void)n_in; (void)out_size;

    const int CHv[5] = {4, 2, 1, 1, 1};   // chunks per strip, per level
    ROff ro;
    {
        int off = 0;
        for (int l = 0; l < 5; ++l) {
            const int H = 512 >> l, OH = H - PAD;
            const int tilesX = (OH + 31) / 32;
            const int tilesY = (OH + CHv[l]*32 - 1) / (CHv[l]*32);
            ro.off[l] = off;
            ro.cnt[l] = tilesX * tilesY * NC;
            ro.inv[l] = 1.f / ((float)NC * OH * OH);
            off += ro.cnt[l];
        }
    }

    for (int l = 0; l < 5; ++l) {
        const int H = 512 >> l, OH = H - PAD;
        const int tilesX = (OH + 31) / 32;
        const int tilesY = (OH + CHv[l]*32 - 1) / (CHv[l]*32);
        const dim3 grid(tilesX * tilesY, NC);
        switch (l) {
        case 0:
            ssim_strip_kernel<4,1><<<grid, 256, 0, stream>>>(
                p1[0], p2[0], p1[1], p2[1], H, OH, tilesX, P, partial, ro.off[0]);
            break;
        case 1:
            ssim_strip_kernel<2,1><<<grid, 256, 0, stream>>>(
                p1[1], p2[1], p1[2], p2[2], H, OH, tilesX, P, partial, ro.off[1]);
            break;
        case 2:
            ssim_strip_kernel<1,1><<<grid, 256, 0, stream>>>(
                p1[2], p2[2], p1[3], p2[3], H, OH, tilesX, P, partial, ro.off[2]);
            break;
        case 3:
            ssim_strip_kernel<1,1><<<grid, 256, 0, stream>>>(
                p1[3], p2[3], p1[4], p2[4], H, OH, tilesX, P, partial, ro.off[3]);
            break;
        default:
            ssim_strip_kernel<1,0><<<grid, 256, 0, stream>>>(
                p1[4], p2[4], nullptr, nullptr, H, OH, tilesX, P, partial, ro.off[4]);
            break;
        }
    }

    reduce_final_kernel<<<1, 256, 0, stream>>>(partial, ro, out);
}